// Round 1
// 666.154 us; speedup vs baseline: 1.0115x; 1.0115x over previous
//
#include <hip/hip_runtime.h>

#define NDIM 512
#define CDIM 128
#define RDIM (NDIM * NDIM)

typedef __attribute__((ext_vector_type(8))) short bf16x8;
typedef __attribute__((ext_vector_type(8))) unsigned short ushort8;
typedef __attribute__((ext_vector_type(4))) float f32x4;

__device__ __forceinline__ float bf2f(unsigned short u) {
  union { unsigned int i; float f; } v; v.i = ((unsigned int)u) << 16; return v.f;
}
__device__ __forceinline__ unsigned short f2bf(float f) {
  union { float f; unsigned int i; } v; v.f = f;
  unsigned int r = v.i + 0x7fffu + ((v.i >> 16) & 1u);
  return (unsigned short)(r >> 16);
}
__device__ __forceinline__ float sigm(float x) { return 1.0f / (1.0f + __expf(-x)); }

// XOR-swizzled [128][128] ushort tile (stride 128, 16B-granule swizzle).
__device__ __forceinline__ int sw(int row, int col) {
  return (row << 7) + ((((col >> 3) ^ (row & 7)) << 3) | (col & 7));
}

// ---------------- k0: weights -> MFMA B-frag blob (consumed by k1 and k3)
// frag(kc,nf), lane L, j: value W[kc*32+(L>>4)*8+j][nf*16+(L&15)]
__global__ __launch_bounds__(256) void k0_prep(
    const float* __restrict__ Wga, const float* __restrict__ Wa,
    const float* __restrict__ Wgb, const float* __restrict__ Wb,
    const float* __restrict__ Wgo, const float* __restrict__ Wo,
    unsigned short* __restrict__ wsF) {
  const float* src;
  switch (blockIdx.x) {
    case 0: src = Wga; break;
    case 1: src = Wa;  break;
    case 2: src = Wgb; break;
    case 3: src = Wb;  break;
    case 4: src = Wgo; break;
    default: src = Wo; break;
  }
  const int t = threadIdx.x;
  unsigned short* dstF = wsF + blockIdx.x * 16384;
  for (int gid = t; gid < 2048; gid += 256) {
    const int fragid = gid >> 6, lane = gid & 63;
    const int kc = fragid >> 3, nf = fragid & 7;
    const int o = nf * 16 + (lane & 15);
    const int c0 = kc * 32 + (lane >> 4) * 8;
#pragma unroll
    for (int j = 0; j < 8; j++) dstF[gid * 8 + j] = f2bf(src[(c0 + j) * CDIM + o]);
  }
}

__device__ __forceinline__ bf16x8 ldfrag(const unsigned short* wf, int slot, int kc,
                                         int nf, int lane) {
  return *((const bf16x8*)(wf + (((slot * 32 + kc * 8 + nf) * 64 + lane) << 3)));
}

// ---------------- k1: LN(z) + 4 projections (a/b pairs only; gate moved to k3) ----
__global__ __launch_bounds__(256, 3) void k1_proj(
    const float* __restrict__ z, const int* __restrict__ mask,
    const float* __restrict__ g_in, const float* __restrict__ b_in,
    const float* __restrict__ bga, const float* __restrict__ ba,
    const float* __restrict__ bgb, const float* __restrict__ bb,
    const unsigned short* __restrict__ wf,
    unsigned short* __restrict__ a_t, unsigned short* __restrict__ b_t) {
  __shared__ unsigned short Xs[CDIM * CDIM];  // 32 KB: zn tile, then transpose buf
  const int t = threadIdx.x;
  const int lane = t & 63;
  const int w = t >> 6;
  const int l15 = lane & 15, lq = lane >> 4;
  const int row0 = blockIdx.x * 128;

  // ---- LN: pass 1 (stats), pass 2 (normalize -> Xs bf16) ----
  {
    const int row = t >> 1, hf = t & 1;
    const float4* zp = (const float4*)(z + (size_t)(row0 + row) * CDIM + hf * 64);
    float s = 0.f, s2 = 0.f;
#pragma unroll
    for (int i = 0; i < 16; i++) {
      float4 x = zp[i];
      s += x.x + x.y + x.z + x.w;
      s2 += x.x * x.x + x.y * x.y + x.z * x.z + x.w * x.w;
    }
    s += __shfl_xor(s, 1);
    s2 += __shfl_xor(s2, 1);
    const float mean = s * 0.0078125f;
    const float var = s2 * 0.0078125f - mean * mean;
    const float rs = rsqrtf(var + 1e-5f);
    const float4* gp = (const float4*)(g_in + hf * 64);
    const float4* bp = (const float4*)(b_in + hf * 64);
#pragma unroll 4
    for (int u = 0; u < 8; u++) {
      float4 x0 = zp[2 * u], x1 = zp[2 * u + 1];
      float4 g0 = gp[2 * u], g1 = gp[2 * u + 1];
      float4 c0 = bp[2 * u], c1 = bp[2 * u + 1];
      ushort8 pk;
      pk[0] = f2bf((x0.x - mean) * rs * g0.x + c0.x);
      pk[1] = f2bf((x0.y - mean) * rs * g0.y + c0.y);
      pk[2] = f2bf((x0.z - mean) * rs * g0.z + c0.z);
      pk[3] = f2bf((x0.w - mean) * rs * g0.w + c0.w);
      pk[4] = f2bf((x1.x - mean) * rs * g1.x + c1.x);
      pk[5] = f2bf((x1.y - mean) * rs * g1.y + c1.y);
      pk[6] = f2bf((x1.z - mean) * rs * g1.z + c1.z);
      pk[7] = f2bf((x1.w - mean) * rs * g1.w + c1.w);
      const int su = (hf * 8 + u) ^ (row & 7);
      *((ushort8*)&Xs[(row << 7) + (su << 3)]) = pk;
    }
  }

  unsigned mbits = 0;
#pragma unroll
  for (int ms = 0; ms < 2; ms++)
#pragma unroll
    for (int r = 0; r < 4; r++) {
      const int rl = w * 32 + ms * 16 + (lq << 2) + r;
      if (mask[row0 + rl] != 0) mbits |= 1u << (ms * 4 + r);
    }

  __syncthreads();

  bf16x8 afr[2][4];
#pragma unroll
  for (int ms = 0; ms < 2; ms++) {
    const int m = w * 32 + ms * 16 + l15;
#pragma unroll
    for (int kc = 0; kc < 4; kc++)
      afr[ms][kc] = *((const bf16x8*)&Xs[sw(m, kc * 32 + (lq << 3))]);
  }
  __syncthreads();  // Xs now reusable as transpose buffer

  const f32x4 zv = {0.f, 0.f, 0.f, 0.f};

  // ---- pairs: (Wga,Wa)->a_t, (Wgb,Wb)->b_t ----
#pragma unroll 1
  for (int pair = 0; pair < 2; pair++) {
    const int sg = pair * 2, sv = pair * 2 + 1;
    const float* bgp = (pair == 0) ? bga : bgb;
    const float* bvp = (pair == 0) ? ba : bb;
#pragma unroll 1
    for (int half = 0; half < 2; half++) {
      f32x4 accg[2][4], accv[2][4];
#pragma unroll
      for (int i = 0; i < 2; i++)
#pragma unroll
        for (int j = 0; j < 4; j++) { accg[i][j] = zv; accv[i][j] = zv; }
#pragma unroll
      for (int kc = 0; kc < 4; kc++) {
#pragma unroll
        for (int nfh = 0; nfh < 4; nfh++) {
          const int fi = half * 4 + nfh;
          bf16x8 bg = ldfrag(wf, sg, kc, fi, lane);
          bf16x8 bv = ldfrag(wf, sv, kc, fi, lane);
          accg[0][nfh] = __builtin_amdgcn_mfma_f32_16x16x32_bf16(afr[0][kc], bg, accg[0][nfh], 0, 0, 0);
          accg[1][nfh] = __builtin_amdgcn_mfma_f32_16x16x32_bf16(afr[1][kc], bg, accg[1][nfh], 0, 0, 0);
          accv[0][nfh] = __builtin_amdgcn_mfma_f32_16x16x32_bf16(afr[0][kc], bv, accv[0][nfh], 0, 0, 0);
          accv[1][nfh] = __builtin_amdgcn_mfma_f32_16x16x32_bf16(afr[1][kc], bv, accv[1][nfh], 0, 0, 0);
        }
      }
#pragma unroll
      for (int ms = 0; ms < 2; ms++)
#pragma unroll
        for (int nfh = 0; nfh < 4; nfh++) {
          const int n = half * 64 + nfh * 16 + l15;
          const float bg = bgp[n], bv = bvp[n];
#pragma unroll
          for (int r = 0; r < 4; r++) {
            const int rl = w * 32 + ms * 16 + (lq << 2) + r;
            float val = sigm(accg[ms][nfh][r] + bg) * (accv[ms][nfh][r] + bv);
            if ((mbits >> (ms * 4 + r)) & 1u) val = 0.f;
            Xs[sw(n, rl)] = f2bf(val);  // transpose buffer [o][row]
          }
        }
    }
    __syncthreads();
    unsigned short* dst = (pair == 0) ? a_t : b_t;
    {
      const int o = t >> 1, hf = t & 1;
#pragma unroll
      for (int u = 0; u < 8; u++) {
        const int ru = hf * 8 + u;
        const int su = ru ^ (o & 7);
        uint4 val = *((const uint4*)&Xs[(o << 7) + (su << 3)]);
        *((uint4*)&dst[(size_t)o * RDIM + row0 + ru * 8]) = val;
      }
    }
    __syncthreads();
  }
}

// ---------------- k2: per-channel NT GEMM (+ XCD-chunked block swizzle) --------
__global__ __launch_bounds__(256) void k2_einsum(
    const unsigned short* __restrict__ a_t, const unsigned short* __restrict__ b_t,
    unsigned short* __restrict__ k_t) {
  __shared__ unsigned short As[128 * 72];
  __shared__ unsigned short Bs[128 * 72];
  const int t = threadIdx.x;
  const int lane = t & 63;
  const int w = t >> 6;
  const int l15 = lane & 15, lq = lane >> 4;
  // chunked XCD-bijective swizzle: nwg=2048, 2048%8==0; XCD x gets a contiguous
  // chunk of 256 logical blocks -> per-XCD L2 keeps whole channel panel sets.
  const int bid = (blockIdx.x & 7) * (2048 >> 3) + (blockIdx.x >> 3);
  const int o = bid >> 4;
  const int tile = bid & 15;
  const int i0 = (tile >> 2) * 128, j0 = (tile & 3) * 128;
  const size_t base = (size_t)o * RDIM;

  f32x4 acc[2][8];
  const f32x4 zv = {0.f, 0.f, 0.f, 0.f};
#pragma unroll
  for (int i = 0; i < 2; i++)
#pragma unroll
    for (int j = 0; j < 8; j++) acc[i][j] = zv;

  const int r = t & 127;
  const int isB = t >> 7;
  const unsigned short* srcp = (isB ? b_t : a_t) + base + (size_t)((isB ? j0 : i0) + r) * NDIM;
  unsigned short* dstp = isB ? &Bs[r * 72] : &As[r * 72];

  for (int k0 = 0; k0 < NDIM; k0 += 64) {
    __syncthreads();
    const uint4* s4 = (const uint4*)(srcp + k0);
#pragma unroll
    for (int u = 0; u < 8; u++) *((uint4*)&dstp[u * 8]) = s4[u];
    __syncthreads();
#pragma unroll
    for (int kc = 0; kc < 2; kc++) {
      const int kk = kc * 32 + (lq << 3);
      bf16x8 a0 = *((const bf16x8*)&As[(w * 32 + l15) * 72 + kk]);
      bf16x8 a1 = *((const bf16x8*)&As[(w * 32 + 16 + l15) * 72 + kk]);
#pragma unroll
      for (int nf = 0; nf < 8; nf++) {
        bf16x8 bfr = *((const bf16x8*)&Bs[(nf * 16 + l15) * 72 + kk]);
        acc[0][nf] = __builtin_amdgcn_mfma_f32_16x16x32_bf16(a0, bfr, acc[0][nf], 0, 0, 0);
        acc[1][nf] = __builtin_amdgcn_mfma_f32_16x16x32_bf16(a1, bfr, acc[1][nf], 0, 0, 0);
      }
    }
  }
#pragma unroll
  for (int ms = 0; ms < 2; ms++)
#pragma unroll
    for (int nf = 0; nf < 8; nf++)
#pragma unroll
      for (int r2 = 0; r2 < 4; r2++) {
        const int mi = i0 + w * 32 + ms * 16 + (lq << 2) + r2;
        const int nj = j0 + nf * 16 + l15;
        k_t[base + (size_t)mi * NDIM + nj] = f2bf(acc[ms][nf][r2]);
      }
}

// ---------------- k3: gate(zn@Wgo) * (LN(k) @ Wo + bo), pure store ----------------
__global__ __launch_bounds__(256, 2) void k3_final(
    const unsigned short* __restrict__ k_t, const unsigned short* __restrict__ wf,
    const float* __restrict__ z, const float* __restrict__ g_in,
    const float* __restrict__ b_in, const float* __restrict__ g_o,
    const float* __restrict__ b_o, const float* __restrict__ bgo,
    const float* __restrict__ bo, float* __restrict__ out) {
  __shared__ unsigned short Ks[CDIM * CDIM];  // k tile [o][row] swizzled
  __shared__ unsigned short XN[CDIM * CDIM];  // zn first, then normalized k
  const int t = threadIdx.x;
  const int lane = t & 63;
  const int w = t >> 6;
  const int l15 = lane & 15, lq = lane >> 4;
  const int row0 = blockIdx.x * 128;

  // stage k tile (transposed source layout [o][row])
  {
    const int o = t >> 1, hf = t & 1;
    const uint4* src = (const uint4*)(k_t + (size_t)o * RDIM + row0 + hf * 64);
#pragma unroll
    for (int u = 0; u < 8; u++) {
      const int ru = hf * 8 + u;
      const int su = ru ^ (o & 7);
      *((uint4*)&Ks[(o << 7) + (su << 3)]) = src[u];
    }
  }
  // recompute LN(z) -> XN (bit-identical to k1's zn path)
  {
    const int row = t >> 1, hf = t & 1;
    const float4* zp = (const float4*)(z + (size_t)(row0 + row) * CDIM + hf * 64);
    float s = 0.f, s2 = 0.f;
#pragma unroll
    for (int i = 0; i < 16; i++) {
      float4 x = zp[i];
      s += x.x + x.y + x.z + x.w;
      s2 += x.x * x.x + x.y * x.y + x.z * x.z + x.w * x.w;
    }
    s += __shfl_xor(s, 1);
    s2 += __shfl_xor(s2, 1);
    const float mean = s * 0.0078125f;
    const float var = s2 * 0.0078125f - mean * mean;
    const float rs = rsqrtf(var + 1e-5f);
    const float4* gp = (const float4*)(g_in + hf * 64);
    const float4* bp = (const float4*)(b_in + hf * 64);
#pragma unroll 4
    for (int u = 0; u < 8; u++) {
      float4 x0 = zp[2 * u], x1 = zp[2 * u + 1];
      float4 g0 = gp[2 * u], g1 = gp[2 * u + 1];
      float4 c0 = bp[2 * u], c1 = bp[2 * u + 1];
      ushort8 pk;
      pk[0] = f2bf((x0.x - mean) * rs * g0.x + c0.x);
      pk[1] = f2bf((x0.y - mean) * rs * g0.y + c0.y);
      pk[2] = f2bf((x0.z - mean) * rs * g0.z + c0.z);
      pk[3] = f2bf((x0.w - mean) * rs * g0.w + c0.w);
      pk[4] = f2bf((x1.x - mean) * rs * g1.x + c1.x);
      pk[5] = f2bf((x1.y - mean) * rs * g1.y + c1.y);
      pk[6] = f2bf((x1.z - mean) * rs * g1.z + c1.z);
      pk[7] = f2bf((x1.w - mean) * rs * g1.w + c1.w);
      const int su = (hf * 8 + u) ^ (row & 7);
      *((ushort8*)&XN[(row << 7) + (su << 3)]) = pk;
    }
  }
  __syncthreads();

  // zn fragments for gate GEMM
  bf16x8 az[2][4];
#pragma unroll
  for (int ms = 0; ms < 2; ms++) {
    const int m = w * 32 + ms * 16 + l15;
#pragma unroll
    for (int kc = 0; kc < 4; kc++)
      az[ms][kc] = *((const bf16x8*)&XN[sw(m, kc * 32 + (lq << 3))]);
  }
  __syncthreads();  // all az reads done; XN reusable

  // per-row (over channels) LayerNorm of k -> XN
  {
    const int row = t >> 1, hf = t & 1;
    float x[64];
    float s = 0.f, s2 = 0.f;
#pragma unroll
    for (int i = 0; i < 64; i++) {
      x[i] = bf2f(Ks[sw(hf * 64 + i, row)]);
      s += x[i];
      s2 += x[i] * x[i];
    }
    s += __shfl_xor(s, 1);
    s2 += __shfl_xor(s2, 1);
    const float mean = s * 0.0078125f;
    const float var = s2 * 0.0078125f - mean * mean;
    const float rs = rsqrtf(var + 1e-5f);
#pragma unroll
    for (int i = 0; i < 64; i++) {
      const int o = hf * 64 + i;
      XN[sw(row, o)] = f2bf((x[i] - mean) * rs * g_o[o] + b_o[o]);
    }
  }
  __syncthreads();

  bf16x8 ak[2][4];
#pragma unroll
  for (int ms = 0; ms < 2; ms++) {
    const int m = w * 32 + ms * 16 + l15;
#pragma unroll
    for (int kc = 0; kc < 4; kc++)
      ak[ms][kc] = *((const bf16x8*)&XN[sw(m, kc * 32 + (lq << 3))]);
  }

  const f32x4 zv = {0.f, 0.f, 0.f, 0.f};
#pragma unroll 1
  for (int half = 0; half < 2; half++) {
    f32x4 accg[2][4], acco[2][4];
#pragma unroll
    for (int i = 0; i < 2; i++)
#pragma unroll
      for (int j = 0; j < 4; j++) { accg[i][j] = zv; acco[i][j] = zv; }
#pragma unroll
    for (int kc = 0; kc < 4; kc++) {
#pragma unroll
      for (int nfh = 0; nfh < 4; nfh++) {
        const int fi = half * 4 + nfh;
        bf16x8 bg = ldfrag(wf, 4, kc, fi, lane);   // Wgo frags
        bf16x8 bw = ldfrag(wf, 5, kc, fi, lane);   // Wo frags
        accg[0][nfh] = __builtin_amdgcn_mfma_f32_16x16x32_bf16(az[0][kc], bg, accg[0][nfh], 0, 0, 0);
        accg[1][nfh] = __builtin_amdgcn_mfma_f32_16x16x32_bf16(az[1][kc], bg, accg[1][nfh], 0, 0, 0);
        acco[0][nfh] = __builtin_amdgcn_mfma_f32_16x16x32_bf16(ak[0][kc], bw, acco[0][nfh], 0, 0, 0);
        acco[1][nfh] = __builtin_amdgcn_mfma_f32_16x16x32_bf16(ak[1][kc], bw, acco[1][nfh], 0, 0, 0);
      }
    }
#pragma unroll
    for (int ms = 0; ms < 2; ms++)
#pragma unroll
      for (int nfh = 0; nfh < 4; nfh++) {
        const int n = half * 64 + nfh * 16 + l15;
        const float gb = bgo[n], ob = bo[n];
#pragma unroll
        for (int r = 0; r < 4; r++) {
          const int rl = w * 32 + ms * 16 + (lq << 2) + r;
          out[(size_t)(row0 + rl) * CDIM + n] =
              sigm(accg[ms][nfh][r] + gb) * (acco[ms][nfh][r] + ob);
        }
      }
  }
}

extern "C" void kernel_launch(void* const* d_in, const int* in_sizes, int n_in,
                              void* d_out, int out_size, void* d_ws, size_t ws_size,
                              hipStream_t stream) {
  const float* z    = (const float*)d_in[0];
  const int*   mask = (const int*)d_in[1];
  const float* g_in = (const float*)d_in[2];
  const float* b_in = (const float*)d_in[3];
  const float* Wa   = (const float*)d_in[4];
  const float* ba   = (const float*)d_in[5];
  const float* Wga  = (const float*)d_in[6];
  const float* bga  = (const float*)d_in[7];
  const float* Wb   = (const float*)d_in[8];
  const float* bb   = (const float*)d_in[9];
  const float* Wgb  = (const float*)d_in[10];
  const float* bgb  = (const float*)d_in[11];
  const float* g_o  = (const float*)d_in[12];
  const float* b_o  = (const float*)d_in[13];
  const float* Wgo  = (const float*)d_in[14];
  const float* bgo  = (const float*)d_in[15];
  const float* Wo   = (const float*)d_in[16];
  const float* bo   = (const float*)d_in[17];
  float* out = (float*)d_out;

  unsigned short* wsF = (unsigned short*)d_ws;           // 6 * frag blobs (k1,k3)
  unsigned short* a_t = wsF + 6 * (CDIM * CDIM);         // [C][N*N] bf16
  unsigned short* b_t = a_t + (size_t)CDIM * RDIM;
  unsigned short* k_t = b_t + (size_t)CDIM * RDIM;

  k0_prep<<<6, 256, 0, stream>>>(Wga, Wa, Wgb, Wb, Wgo, Wo, wsF);
  k1_proj<<<RDIM / 128, 256, 0, stream>>>(z, mask, g_in, b_in, bga, ba, bgb, bb,
                                          wsF, a_t, b_t);
  k2_einsum<<<CDIM * 16, 256, 0, stream>>>(a_t, b_t, k_t);
  k3_final<<<RDIM / 128, 256, 0, stream>>>(k_t, wsF, z, g_in, b_in, g_o, b_o,
                                           bgo, bo, out);
}

// Round 2
// 574.696 us; speedup vs baseline: 1.1725x; 1.1591x over previous
//
#include <hip/hip_runtime.h>

#define NDIM 512
#define CDIM 128
#define RDIM (NDIM * NDIM)

typedef __attribute__((ext_vector_type(8))) short bf16x8;
typedef __attribute__((ext_vector_type(8))) unsigned short ushort8;
typedef __attribute__((ext_vector_type(4))) float f32x4;

__device__ __forceinline__ float bf2f(unsigned short u) {
  union { unsigned int i; float f; } v; v.i = ((unsigned int)u) << 16; return v.f;
}
__device__ __forceinline__ unsigned short f2bf(float f) {
  union { float f; unsigned int i; } v; v.f = f;
  unsigned int r = v.i + 0x7fffu + ((v.i >> 16) & 1u);
  return (unsigned short)(r >> 16);
}
__device__ __forceinline__ float sigm(float x) { return 1.0f / (1.0f + __expf(-x)); }

// XOR-swizzled [128][128] ushort tile (stride 128, 16B-granule swizzle).
__device__ __forceinline__ int sw(int row, int col) {
  return (row << 7) + ((((col >> 3) ^ (row & 7)) << 3) | (col & 7));
}

// async global->LDS, 16B per lane; LDS dest is wave-uniform base + lane*16
__device__ __forceinline__ void gld_lds16(const unsigned short* g, unsigned short* l) {
  __builtin_amdgcn_global_load_lds(
      (const __attribute__((address_space(1))) unsigned int*)g,
      (__attribute__((address_space(3))) unsigned int*)l, 16, 0, 0);
}

// ---------------- k0: weights -> MFMA B-frag blob (consumed by k1 and k3)
__global__ __launch_bounds__(256) void k0_prep(
    const float* __restrict__ Wga, const float* __restrict__ Wa,
    const float* __restrict__ Wgb, const float* __restrict__ Wb,
    const float* __restrict__ Wgo, const float* __restrict__ Wo,
    unsigned short* __restrict__ wsF) {
  const float* src;
  switch (blockIdx.x) {
    case 0: src = Wga; break;
    case 1: src = Wa;  break;
    case 2: src = Wgb; break;
    case 3: src = Wb;  break;
    case 4: src = Wgo; break;
    default: src = Wo; break;
  }
  const int t = threadIdx.x;
  unsigned short* dstF = wsF + blockIdx.x * 16384;
  for (int gid = t; gid < 2048; gid += 256) {
    const int fragid = gid >> 6, lane = gid & 63;
    const int kc = fragid >> 3, nf = fragid & 7;
    const int o = nf * 16 + (lane & 15);
    const int c0 = kc * 32 + (lane >> 4) * 8;
#pragma unroll
    for (int j = 0; j < 8; j++) dstF[gid * 8 + j] = f2bf(src[(c0 + j) * CDIM + o]);
  }
}

__device__ __forceinline__ bf16x8 ldfrag(const unsigned short* wf, int slot, int kc,
                                         int nf, int lane) {
  return *((const bf16x8*)(wf + (((slot * 32 + kc * 8 + nf) * 64 + lane) << 3)));
}

// ---------------- k1: LN(z) + 4 projections (unchanged this round) ----------------
__global__ __launch_bounds__(256, 3) void k1_proj(
    const float* __restrict__ z, const int* __restrict__ mask,
    const float* __restrict__ g_in, const float* __restrict__ b_in,
    const float* __restrict__ bga, const float* __restrict__ ba,
    const float* __restrict__ bgb, const float* __restrict__ bb,
    const unsigned short* __restrict__ wf,
    unsigned short* __restrict__ a_t, unsigned short* __restrict__ b_t) {
  __shared__ unsigned short Xs[CDIM * CDIM];
  const int t = threadIdx.x;
  const int lane = t & 63;
  const int w = t >> 6;
  const int l15 = lane & 15, lq = lane >> 4;
  const int row0 = blockIdx.x * 128;

  {
    const int row = t >> 1, hf = t & 1;
    const float4* zp = (const float4*)(z + (size_t)(row0 + row) * CDIM + hf * 64);
    float s = 0.f, s2 = 0.f;
#pragma unroll
    for (int i = 0; i < 16; i++) {
      float4 x = zp[i];
      s += x.x + x.y + x.z + x.w;
      s2 += x.x * x.x + x.y * x.y + x.z * x.z + x.w * x.w;
    }
    s += __shfl_xor(s, 1);
    s2 += __shfl_xor(s2, 1);
    const float mean = s * 0.0078125f;
    const float var = s2 * 0.0078125f - mean * mean;
    const float rs = rsqrtf(var + 1e-5f);
    const float4* gp = (const float4*)(g_in + hf * 64);
    const float4* bp = (const float4*)(b_in + hf * 64);
#pragma unroll 4
    for (int u = 0; u < 8; u++) {
      float4 x0 = zp[2 * u], x1 = zp[2 * u + 1];
      float4 g0 = gp[2 * u], g1 = gp[2 * u + 1];
      float4 c0 = bp[2 * u], c1 = bp[2 * u + 1];
      ushort8 pk;
      pk[0] = f2bf((x0.x - mean) * rs * g0.x + c0.x);
      pk[1] = f2bf((x0.y - mean) * rs * g0.y + c0.y);
      pk[2] = f2bf((x0.z - mean) * rs * g0.z + c0.z);
      pk[3] = f2bf((x0.w - mean) * rs * g0.w + c0.w);
      pk[4] = f2bf((x1.x - mean) * rs * g1.x + c1.x);
      pk[5] = f2bf((x1.y - mean) * rs * g1.y + c1.y);
      pk[6] = f2bf((x1.z - mean) * rs * g1.z + c1.z);
      pk[7] = f2bf((x1.w - mean) * rs * g1.w + c1.w);
      const int su = (hf * 8 + u) ^ (row & 7);
      *((ushort8*)&Xs[(row << 7) + (su << 3)]) = pk;
    }
  }

  unsigned mbits = 0;
#pragma unroll
  for (int ms = 0; ms < 2; ms++)
#pragma unroll
    for (int r = 0; r < 4; r++) {
      const int rl = w * 32 + ms * 16 + (lq << 2) + r;
      if (mask[row0 + rl] != 0) mbits |= 1u << (ms * 4 + r);
    }

  __syncthreads();

  bf16x8 afr[2][4];
#pragma unroll
  for (int ms = 0; ms < 2; ms++) {
    const int m = w * 32 + ms * 16 + l15;
#pragma unroll
    for (int kc = 0; kc < 4; kc++)
      afr[ms][kc] = *((const bf16x8*)&Xs[sw(m, kc * 32 + (lq << 3))]);
  }
  __syncthreads();

  const f32x4 zv = {0.f, 0.f, 0.f, 0.f};

#pragma unroll 1
  for (int pair = 0; pair < 2; pair++) {
    const int sg = pair * 2, sv = pair * 2 + 1;
    const float* bgp = (pair == 0) ? bga : bgb;
    const float* bvp = (pair == 0) ? ba : bb;
#pragma unroll 1
    for (int half = 0; half < 2; half++) {
      f32x4 accg[2][4], accv[2][4];
#pragma unroll
      for (int i = 0; i < 2; i++)
#pragma unroll
        for (int j = 0; j < 4; j++) { accg[i][j] = zv; accv[i][j] = zv; }
#pragma unroll
      for (int kc = 0; kc < 4; kc++) {
#pragma unroll
        for (int nfh = 0; nfh < 4; nfh++) {
          const int fi = half * 4 + nfh;
          bf16x8 bg = ldfrag(wf, sg, kc, fi, lane);
          bf16x8 bv = ldfrag(wf, sv, kc, fi, lane);
          accg[0][nfh] = __builtin_amdgcn_mfma_f32_16x16x32_bf16(afr[0][kc], bg, accg[0][nfh], 0, 0, 0);
          accg[1][nfh] = __builtin_amdgcn_mfma_f32_16x16x32_bf16(afr[1][kc], bg, accg[1][nfh], 0, 0, 0);
          accv[0][nfh] = __builtin_amdgcn_mfma_f32_16x16x32_bf16(afr[0][kc], bv, accv[0][nfh], 0, 0, 0);
          accv[1][nfh] = __builtin_amdgcn_mfma_f32_16x16x32_bf16(afr[1][kc], bv, accv[1][nfh], 0, 0, 0);
        }
      }
#pragma unroll
      for (int ms = 0; ms < 2; ms++)
#pragma unroll
        for (int nfh = 0; nfh < 4; nfh++) {
          const int n = half * 64 + nfh * 16 + l15;
          const float bg = bgp[n], bv = bvp[n];
#pragma unroll
          for (int r = 0; r < 4; r++) {
            const int rl = w * 32 + ms * 16 + (lq << 2) + r;
            float val = sigm(accg[ms][nfh][r] + bg) * (accv[ms][nfh][r] + bv);
            if ((mbits >> (ms * 4 + r)) & 1u) val = 0.f;
            Xs[sw(n, rl)] = f2bf(val);
          }
        }
    }
    __syncthreads();
    unsigned short* dst = (pair == 0) ? a_t : b_t;
    {
      const int o = t >> 1, hf = t & 1;
#pragma unroll
      for (int u = 0; u < 8; u++) {
        const int ru = hf * 8 + u;
        const int su = ru ^ (o & 7);
        uint4 val = *((const uint4*)&Xs[(o << 7) + (su << 3)]);
        *((uint4*)&dst[(size_t)o * RDIM + row0 + ru * 8]) = val;
      }
    }
    __syncthreads();
  }
}

// ---------------- k2: 256x256-tile NT GEMM, global_load_lds + 2-phase dbuf ------
// LDS rows are LINEAR 64-ushort (128B); 16B granule g holds global granule
// g^(row&7) (pre-swizzled source); ds_read applies the same XOR -> conflict-free.
__global__ __launch_bounds__(512, 1) void k2_einsum(
    const unsigned short* __restrict__ a_t, const unsigned short* __restrict__ b_t,
    unsigned short* __restrict__ k_t) {
  __shared__ unsigned short S[2][2][256 * 64];  // [buf][A=0/B=1][row*64+k] : 128 KiB
  const int t = threadIdx.x;
  const int lane = t & 63;
  const int wid = t >> 6;              // 8 waves
  const int l15 = lane & 15, lq = lane >> 4;
  // chunked XCD-bijective swizzle (512 % 8 == 0)
  const int bid = (blockIdx.x & 7) * 64 + (blockIdx.x >> 3);
  const int o = bid >> 2;
  const int tile = bid & 3;
  const int i0 = (tile >> 1) * 256, j0 = (tile & 1) * 256;
  const size_t base = (size_t)o * RDIM;
  const int wr = wid >> 2, wc = wid & 3;  // 2x4 wave grid; per-wave 128x64 output

  // staging geometry: wave w stages chunks w*4..w*4+3 of A and of B (1 KiB each)
  const int srow = lane >> 3;                    // row within 8-row chunk
  const int sgl = (lane & 7) ^ srow;             // pre-swizzled source granule

  f32x4 acc[8][4];
  const f32x4 zv = {0.f, 0.f, 0.f, 0.f};
#pragma unroll
  for (int i = 0; i < 8; i++)
#pragma unroll
    for (int j = 0; j < 4; j++) acc[i][j] = zv;

  auto stage = [&](int buf, int k0) {
#pragma unroll
    for (int c = 0; c < 4; c++) {
      const int chunk = wid * 4 + c;             // 0..31, 8 rows each
      const int row = chunk * 8 + srow;
      gld_lds16(a_t + base + (size_t)(i0 + row) * NDIM + k0 + sgl * 8,
                &S[buf][0][chunk * 512]);
      gld_lds16(b_t + base + (size_t)(j0 + row) * NDIM + k0 + sgl * 8,
                &S[buf][1][chunk * 512]);
    }
  };

  stage(0, 0);
  __syncthreads();  // drains vmcnt(0): buf0 ready

#pragma unroll 1
  for (int ks = 0; ks < 8; ks++) {
    const int cur = ks & 1;
    if (ks < 7) stage(cur ^ 1, (ks + 1) * 64);   // prefetch next K-step
    const unsigned short* Ab = &S[cur][0][0];
    const unsigned short* Bb = &S[cur][1][0];
#pragma unroll
    for (int kc = 0; kc < 2; kc++) {
      const int g = kc * 4 + lq;                 // logical 16B granule in row
      bf16x8 bfr[4];
#pragma unroll
      for (int nf = 0; nf < 4; nf++) {
        const int rb = wc * 64 + nf * 16 + l15;
        bfr[nf] = *((const bf16x8*)&Bb[rb * 64 + ((g ^ (rb & 7)) << 3)]);
      }
#pragma unroll
      for (int mf = 0; mf < 8; mf++) {
        const int ra = wr * 128 + mf * 16 + l15;
        bf16x8 af = *((const bf16x8*)&Ab[ra * 64 + ((g ^ (ra & 7)) << 3)]);
#pragma unroll
        for (int nf = 0; nf < 4; nf++)
          acc[mf][nf] = __builtin_amdgcn_mfma_f32_16x16x32_bf16(af, bfr[nf], acc[mf][nf], 0, 0, 0);
      }
    }
    __syncthreads();  // drains vmcnt(0)+lgkmcnt(0): prefetched buf ready, reads done
  }

#pragma unroll
  for (int mf = 0; mf < 8; mf++)
#pragma unroll
    for (int nf = 0; nf < 4; nf++)
#pragma unroll
      for (int r2 = 0; r2 < 4; r2++) {
        const int mi = i0 + wr * 128 + mf * 16 + (lq << 2) + r2;
        const int nj = j0 + wc * 64 + nf * 16 + l15;
        k_t[base + (size_t)mi * NDIM + nj] = f2bf(acc[mf][nf][r2]);
      }
}

// ---------------- k3: gate(zn@Wgo) * (LN(k) @ Wo + bo), pure store ----------------
__global__ __launch_bounds__(256, 2) void k3_final(
    const unsigned short* __restrict__ k_t, const unsigned short* __restrict__ wf,
    const float* __restrict__ z, const float* __restrict__ g_in,
    const float* __restrict__ b_in, const float* __restrict__ g_o,
    const float* __restrict__ b_o, const float* __restrict__ bgo,
    const float* __restrict__ bo, float* __restrict__ out) {
  __shared__ unsigned short Ks[CDIM * CDIM];
  __shared__ unsigned short XN[CDIM * CDIM];
  const int t = threadIdx.x;
  const int lane = t & 63;
  const int w = t >> 6;
  const int l15 = lane & 15, lq = lane >> 4;
  const int row0 = blockIdx.x * 128;

  {
    const int o = t >> 1, hf = t & 1;
    const uint4* src = (const uint4*)(k_t + (size_t)o * RDIM + row0 + hf * 64);
#pragma unroll
    for (int u = 0; u < 8; u++) {
      const int ru = hf * 8 + u;
      const int su = ru ^ (o & 7);
      *((uint4*)&Ks[(o << 7) + (su << 3)]) = src[u];
    }
  }
  {
    const int row = t >> 1, hf = t & 1;
    const float4* zp = (const float4*)(z + (size_t)(row0 + row) * CDIM + hf * 64);
    float s = 0.f, s2 = 0.f;
#pragma unroll
    for (int i = 0; i < 16; i++) {
      float4 x = zp[i];
      s += x.x + x.y + x.z + x.w;
      s2 += x.x * x.x + x.y * x.y + x.z * x.z + x.w * x.w;
    }
    s += __shfl_xor(s, 1);
    s2 += __shfl_xor(s2, 1);
    const float mean = s * 0.0078125f;
    const float var = s2 * 0.0078125f - mean * mean;
    const float rs = rsqrtf(var + 1e-5f);
    const float4* gp = (const float4*)(g_in + hf * 64);
    const float4* bp = (const float4*)(b_in + hf * 64);
#pragma unroll 4
    for (int u = 0; u < 8; u++) {
      float4 x0 = zp[2 * u], x1 = zp[2 * u + 1];
      float4 g0 = gp[2 * u], g1 = gp[2 * u + 1];
      float4 c0 = bp[2 * u], c1 = bp[2 * u + 1];
      ushort8 pk;
      pk[0] = f2bf((x0.x - mean) * rs * g0.x + c0.x);
      pk[1] = f2bf((x0.y - mean) * rs * g0.y + c0.y);
      pk[2] = f2bf((x0.z - mean) * rs * g0.z + c0.z);
      pk[3] = f2bf((x0.w - mean) * rs * g0.w + c0.w);
      pk[4] = f2bf((x1.x - mean) * rs * g1.x + c1.x);
      pk[5] = f2bf((x1.y - mean) * rs * g1.y + c1.y);
      pk[6] = f2bf((x1.z - mean) * rs * g1.z + c1.z);
      pk[7] = f2bf((x1.w - mean) * rs * g1.w + c1.w);
      const int su = (hf * 8 + u) ^ (row & 7);
      *((ushort8*)&XN[(row << 7) + (su << 3)]) = pk;
    }
  }
  __syncthreads();

  bf16x8 az[2][4];
#pragma unroll
  for (int ms = 0; ms < 2; ms++) {
    const int m = w * 32 + ms * 16 + l15;
#pragma unroll
    for (int kc = 0; kc < 4; kc++)
      az[ms][kc] = *((const bf16x8*)&XN[sw(m, kc * 32 + (lq << 3))]);
  }
  __syncthreads();

  {
    const int row = t >> 1, hf = t & 1;
    float x[64];
    float s = 0.f, s2 = 0.f;
#pragma unroll
    for (int i = 0; i < 64; i++) {
      x[i] = bf2f(Ks[sw(hf * 64 + i, row)]);
      s += x[i];
      s2 += x[i] * x[i];
    }
    s += __shfl_xor(s, 1);
    s2 += __shfl_xor(s2, 1);
    const float mean = s * 0.0078125f;
    const float var = s2 * 0.0078125f - mean * mean;
    const float rs = rsqrtf(var + 1e-5f);
#pragma unroll
    for (int i = 0; i < 64; i++) {
      const int o = hf * 64 + i;
      XN[sw(row, o)] = f2bf((x[i] - mean) * rs * g_o[o] + b_o[o]);
    }
  }
  __syncthreads();

  bf16x8 ak[2][4];
#pragma unroll
  for (int ms = 0; ms < 2; ms++) {
    const int m = w * 32 + ms * 16 + l15;
#pragma unroll
    for (int kc = 0; kc < 4; kc++)
      ak[ms][kc] = *((const bf16x8*)&XN[sw(m, kc * 32 + (lq << 3))]);
  }

  const f32x4 zv = {0.f, 0.f, 0.f, 0.f};
#pragma unroll 1
  for (int half = 0; half < 2; half++) {
    f32x4 accg[2][4], acco[2][4];
#pragma unroll
    for (int i = 0; i < 2; i++)
#pragma unroll
      for (int j = 0; j < 4; j++) { accg[i][j] = zv; acco[i][j] = zv; }
#pragma unroll
    for (int kc = 0; kc < 4; kc++) {
#pragma unroll
      for (int nfh = 0; nfh < 4; nfh++) {
        const int fi = half * 4 + nfh;
        bf16x8 bg = ldfrag(wf, 4, kc, fi, lane);
        bf16x8 bw = ldfrag(wf, 5, kc, fi, lane);
        accg[0][nfh] = __builtin_amdgcn_mfma_f32_16x16x32_bf16(az[0][kc], bg, accg[0][nfh], 0, 0, 0);
        accg[1][nfh] = __builtin_amdgcn_mfma_f32_16x16x32_bf16(az[1][kc], bg, accg[1][nfh], 0, 0, 0);
        acco[0][nfh] = __builtin_amdgcn_mfma_f32_16x16x32_bf16(ak[0][kc], bw, acco[0][nfh], 0, 0, 0);
        acco[1][nfh] = __builtin_amdgcn_mfma_f32_16x16x32_bf16(ak[1][kc], bw, acco[1][nfh], 0, 0, 0);
      }
    }
#pragma unroll
    for (int ms = 0; ms < 2; ms++)
#pragma unroll
      for (int nfh = 0; nfh < 4; nfh++) {
        const int n = half * 64 + nfh * 16 + l15;
        const float gb = bgo[n], ob = bo[n];
#pragma unroll
        for (int r = 0; r < 4; r++) {
          const int rl = w * 32 + ms * 16 + (lq << 2) + r;
          out[(size_t)(row0 + rl) * CDIM + n] =
              sigm(accg[ms][nfh][r] + gb) * (acco[ms][nfh][r] + ob);
        }
      }
  }
}

extern "C" void kernel_launch(void* const* d_in, const int* in_sizes, int n_in,
                              void* d_out, int out_size, void* d_ws, size_t ws_size,
                              hipStream_t stream) {
  const float* z    = (const float*)d_in[0];
  const int*   mask = (const int*)d_in[1];
  const float* g_in = (const float*)d_in[2];
  const float* b_in = (const float*)d_in[3];
  const float* Wa   = (const float*)d_in[4];
  const float* ba   = (const float*)d_in[5];
  const float* Wga  = (const float*)d_in[6];
  const float* bga  = (const float*)d_in[7];
  const float* Wb   = (const float*)d_in[8];
  const float* bb   = (const float*)d_in[9];
  const float* Wgb  = (const float*)d_in[10];
  const float* bgb  = (const float*)d_in[11];
  const float* g_o  = (const float*)d_in[12];
  const float* b_o  = (const float*)d_in[13];
  const float* Wgo  = (const float*)d_in[14];
  const float* bgo  = (const float*)d_in[15];
  const float* Wo   = (const float*)d_in[16];
  const float* bo   = (const float*)d_in[17];
  float* out = (float*)d_out;

  unsigned short* wsF = (unsigned short*)d_ws;
  unsigned short* a_t = wsF + 6 * (CDIM * CDIM);
  unsigned short* b_t = a_t + (size_t)CDIM * RDIM;
  unsigned short* k_t = b_t + (size_t)CDIM * RDIM;

  k0_prep<<<6, 256, 0, stream>>>(Wga, Wa, Wgb, Wb, Wgo, Wo, wsF);
  k1_proj<<<RDIM / 128, 256, 0, stream>>>(z, mask, g_in, b_in, bga, ba, bgb, bb,
                                          wsF, a_t, b_t);
  k2_einsum<<<512, 512, 0, stream>>>(a_t, b_t, k_t);
  k3_final<<<RDIM / 128, 256, 0, stream>>>(k_t, wsF, z, g_in, b_in, g_o, b_o,
                                           bgo, bo, out);
}